// Round 12
// baseline (229.221 us; speedup 1.0000x reference)
//
#include <hip/hip_runtime.h>
#include <hip/hip_fp16.h>
#include <math.h>

#define NN 8192
#define DD 768
#define CC 256
#define PP 16384
#define NG 256            // 64-wide codebook groups
#define MARGIN 5.0e-3f    // > 2*eps_dist(fp16)=2e-3
#define BETA_C 1.25f
#define EPS_C 1e-12f

typedef __attribute__((ext_vector_type(8))) _Float16 f16x8;
typedef __attribute__((ext_vector_type(8))) short bf16x8;
typedef __attribute__((ext_vector_type(16))) float f32x16;

static __device__ __forceinline__ ushort f2h(float x) {
    _Float16 h = (_Float16)x;            // RNE
    return __builtin_bit_cast(unsigned short, h);
}
static __device__ __forceinline__ ushort f2bf(float x) {
    unsigned u = __float_as_uint(x);
    return (ushort)((u + 0x7fffu + ((u >> 16) & 1u)) >> 16);
}

static __device__ __forceinline__ void gload_lds16(const void* g, void* l) {
    __builtin_amdgcn_global_load_lds(
        (const __attribute__((address_space(1))) unsigned int*)g,
        (__attribute__((address_space(3))) unsigned int*)l, 16, 0, 0);
}

// ---------------------------------------------------------------------------
// Kernel 1 (fused): zq = normalize(z @ W_in + b_in), f32 + fp16 outputs.
// 16 rows x 256 cols per block (full row -> in-kernel normalize). BITWISE
// identical to the old gemm_in + norm2 pair: per-element adds stay k-
// ascending; the norm reduction replicates the old 64-lane xor tree exactly
// (old lane l = 16c + tj: levels 32,16 = in-thread c^2,c^1; levels 8,4,2,1 =
// lane xor over tj).
// ---------------------------------------------------------------------------
__global__ __launch_bounds__(256) void k_gemm_in_norm(const float* __restrict__ z,
    const float* __restrict__ W, const float* __restrict__ b,
    float* __restrict__ zq, ushort* __restrict__ zqh)
{
    __shared__ float zt[16][36];
    __shared__ float wt[32][260];
    const int t = threadIdx.x;
    const int ti = t >> 4, tj = t & 15;   // row 0..15, col-group 0..15
    const int n0 = blockIdx.x * 16;

    float acc[16];
#pragma unroll
    for (int c = 0; c < 16; ++c) acc[c] = 0.f;

    for (int k0 = 0; k0 < DD; k0 += 32) {
        __syncthreads();
        if (t < 128) {                     // z tile: 16x32 = 128 float4
            int row = t >> 3, c4 = t & 7;
            *reinterpret_cast<float4*>(&zt[row][c4 * 4]) =
                *reinterpret_cast<const float4*>(&z[(size_t)(n0 + row) * DD + k0 + c4 * 4]);
        }
#pragma unroll
        for (int l = 0; l < 8; ++l) {      // W tile: 32x256 = 2048 float4
            int idx = l * 256 + t;
            int krow = idx >> 6, w4 = idx & 63;
            *reinterpret_cast<float4*>(&wt[krow][w4 * 4]) =
                *reinterpret_cast<const float4*>(&W[(size_t)(k0 + krow) * CC + w4 * 4]);
        }
        __syncthreads();
#pragma unroll
        for (int kk = 0; kk < 32; kk += 4) {
            float4 a4 = *reinterpret_cast<const float4*>(&zt[ti][kk]);
#pragma unroll
            for (int q = 0; q < 4; ++q) {
                float av = ((const float*)&a4)[q];
#pragma unroll
                for (int c = 0; c < 4; ++c) {
                    float4 wv = *reinterpret_cast<const float4*>(&wt[kk + q][c * 64 + tj * 4]);
                    acc[c * 4 + 0] += av * wv.x;
                    acc[c * 4 + 1] += av * wv.y;
                    acc[c * 4 + 2] += av * wv.z;
                    acc[c * 4 + 3] += av * wv.w;
                }
            }
        }
    }

    // bias + per-4-col square partials (p[c] == old lane (16c+tj) partial)
    float p[4];
#pragma unroll
    for (int c = 0; c < 4; ++c) {
        const int col = c * 64 + tj * 4;
        acc[c * 4 + 0] += b[col + 0];
        acc[c * 4 + 1] += b[col + 1];
        acc[c * 4 + 2] += b[col + 2];
        acc[c * 4 + 3] += b[col + 3];
        p[c] = acc[c * 4 + 0] * acc[c * 4 + 0] + acc[c * 4 + 1] * acc[c * 4 + 1]
             + acc[c * 4 + 2] * acc[c * 4 + 2] + acc[c * 4 + 3] * acc[c * 4 + 3];
    }
    // old tree: off32 -> c^2 ; off16 -> c^1 ; off 8,4,2,1 -> lane xor (tj bits)
    float s0 = p[0] + p[2];
    float s1 = p[1] + p[3];
    float s = s0 + s1;
#pragma unroll
    for (int off = 8; off; off >>= 1) s += __shfl_xor(s, off, 64);
    const float r = 1.0f / sqrtf(s + EPS_C);

#pragma unroll
    for (int c = 0; c < 4; ++c) {
        const int col = c * 64 + tj * 4;
        float4 v;
        v.x = acc[c * 4 + 0] * r;
        v.y = acc[c * 4 + 1] * r;
        v.z = acc[c * 4 + 2] * r;
        v.w = acc[c * 4 + 3] * r;
        *reinterpret_cast<float4*>(&zq[(size_t)(n0 + ti) * CC + col]) = v;
        ushort4 hv;
        hv.x = f2h(v.x); hv.y = f2h(v.y); hv.z = f2h(v.z); hv.w = f2h(v.w);
        *reinterpret_cast<ushort4*>(&zqh[(size_t)(n0 + ti) * CC + col]) = hv;
    }
}

// ---------------------------------------------------------------------------
// Kernel 2 (merged prep): blocks [0,4096): codebook normalize -> cbh (fp16),
// cz2, rinv. Blocks [4096,4144): W_out split -> transposed hi bf16 [768][256].
// ---------------------------------------------------------------------------
__global__ __launch_bounds__(256) void k_prep(const float* __restrict__ codebook,
    ushort* __restrict__ cbh, float* __restrict__ cz2, float* __restrict__ rinv,
    const float* __restrict__ W, ushort* __restrict__ wthi)
{
    __shared__ float tile[64][68];
    const int t = threadIdx.x;
    if (blockIdx.x < 4096) {
        const int wave = t >> 6;
        const int lane = t & 63;
        const int row = blockIdx.x * 4 + wave;
        float4 v = *reinterpret_cast<const float4*>(&codebook[(size_t)row * CC + lane * 4]);
        float s = v.x * v.x + v.y * v.y + v.z * v.z + v.w * v.w;
#pragma unroll
        for (int off = 32; off; off >>= 1) s += __shfl_xor(s, off, 64);
        float r = 1.0f / sqrtf(s + EPS_C);
        v.x *= r; v.y *= r; v.z *= r; v.w *= r;
        ushort4 hv;
        hv.x = f2h(v.x); hv.y = f2h(v.y); hv.z = f2h(v.z); hv.w = f2h(v.w);
        *reinterpret_cast<ushort4*>(&cbh[(size_t)row * CC + lane * 4]) = hv;
        float s2 = v.x * v.x + v.y * v.y + v.z * v.z + v.w * v.w;
#pragma unroll
        for (int off = 32; off; off >>= 1) s2 += __shfl_xor(s2, off, 64);
        if (lane == 0) {
            cz2[row] = s2;
            rinv[row] = r;
        }
    } else {
        const int id = blockIdx.x - 4096;          // 0..47
        const int d0 = (id % 12) * 64;
        const int k0 = (id / 12) * 64;
#pragma unroll
        for (int i = 0; i < 16; ++i) {
            int row = i * 4 + (t >> 6);
            int col = t & 63;
            tile[row][col] = W[(size_t)(k0 + row) * DD + d0 + col];
        }
        __syncthreads();
#pragma unroll
        for (int i = 0; i < 16; ++i) {
            int drow = i * 4 + (t >> 6);
            int kc = t & 63;
            wthi[(size_t)(d0 + drow) * CC + k0 + kc] = f2bf(tile[kc][drow]);
        }
    }
}

// ---------------------------------------------------------------------------
// Kernel 3: fp16 MFMA approx distances — the VERIFIED R8 kernel, verbatim
// (256p x 128n, 4 waves, BK=32, 2 x 24 KB LDS dbuf, counted vmcnt(6),
// XOR-swizzled rows, 2D grid). 97 us / MfmaUtil 31% / FETCH 23 MB.
// ---------------------------------------------------------------------------
__global__ __launch_bounds__(256) void k_dist(
    const ushort* __restrict__ cbh, const ushort* __restrict__ zqh,
    const float* __restrict__ cz2,
    float* __restrict__ gmin, unsigned long long* __restrict__ maskA)
{
    __shared__ ushort lds[2][12288];  // 48 KB total
    const int t = threadIdx.x;
    const int lane = t & 63;
    const int w = t >> 6;             // wave 0..3
    const int wr = w >> 1;            // p half (128 rows)
    const int wc = w & 1;             // n half (64 cols)
    const int p0 = blockIdx.x * 256;
    const int n0 = blockIdx.y * 128;
    const int kh = lane >> 5;
    const int r31 = lane & 31;

    // acc init with -cz2/2
    f32x16 acc[4][2];
#pragma unroll
    for (int mi = 0; mi < 4; ++mi) {
        const int pbm = p0 + wr * 128 + mi * 32;
#pragma unroll
        for (int q = 0; q < 4; ++q) {
            float4 cz = *reinterpret_cast<const float4*>(&cz2[pbm + q * 8 + kh * 4]);
#pragma unroll
            for (int j = 0; j < 4; ++j) {
                float v = -0.5f * ((const float*)&cz.x)[j];
                acc[mi][0][q * 4 + j] = v;
                acc[mi][1][q * 4 + j] = v;
            }
        }
    }

    // staging sources (pre-swizzled global; mapping verified R6/R8)
    const int u_l = lane >> 3;
    const int e = (lane & 7) ^ u_l;
    const int hh = e >> 2, jj = e & 3;
    const ushort* srcA[4];
    const ushort* srcB[2];
#pragma unroll
    for (int i = 0; i < 4; ++i)
        srcA[i] = cbh + (size_t)(p0 + 2 * (w * 32 + i * 8 + u_l) + hh) * CC + jj * 8;
#pragma unroll
    for (int i = 0; i < 2; ++i)
        srcB[i] = zqh + (size_t)(n0 + 2 * (w * 16 + i * 8 + u_l) + hh) * CC + jj * 8;

#define STAGE(BUF, KT)                                                        \
    {                                                                         \
        _Pragma("unroll")                                                     \
        for (int i = 0; i < 4; ++i)                                           \
            gload_lds16(srcA[i] + (KT) * 32, &lds[BUF][(w * 32 + i * 8) * 64]); \
        _Pragma("unroll")                                                     \
        for (int i = 0; i < 2; ++i)                                           \
            gload_lds16(srcB[i] + (KT) * 32, &lds[BUF][8192 + (w * 16 + i * 8) * 64]); \
    }

    // read-side addressing (verified R6/R8)
    const int ua = wr * 64 + (r31 >> 1);   // + mi*16
    const int ub = wc * 32 + (r31 >> 1);   // + ni*16
    const int hb = (r31 & 1) * 4 + kh;     // + ks*2

#define COMPUTE(BUF)                                                          \
    {                                                                         \
        _Pragma("unroll")                                                     \
        for (int ks = 0; ks < 2; ++ks) {                                      \
            f16x8 af[4], bfv[2];                                              \
            _Pragma("unroll")                                                 \
            for (int mi = 0; mi < 4; ++mi) {                                  \
                int u = ua + mi * 16;                                         \
                af[mi] = *reinterpret_cast<const f16x8*>(                     \
                    &lds[BUF][u * 64 + (((hb + ks * 2) ^ (u & 7)) * 8)]);     \
            }                                                                 \
            _Pragma("unroll")                                                 \
            for (int ni = 0; ni < 2; ++ni) {                                  \
                int u = ub + ni * 16;                                         \
                bfv[ni] = *reinterpret_cast<const f16x8*>(                    \
                    &lds[BUF][8192 + u * 64 + (((hb + ks * 2) ^ (u & 7)) * 8)]); \
            }                                                                 \
            __builtin_amdgcn_s_setprio(1);                                    \
            acc[0][0] = __builtin_amdgcn_mfma_f32_32x32x16_f16(af[0], bfv[0], acc[0][0], 0, 0, 0); \
            acc[0][1] = __builtin_amdgcn_mfma_f32_32x32x16_f16(af[0], bfv[1], acc[0][1], 0, 0, 0); \
            acc[1][0] = __builtin_amdgcn_mfma_f32_32x32x16_f16(af[1], bfv[0], acc[1][0], 0, 0, 0); \
            acc[1][1] = __builtin_amdgcn_mfma_f32_32x32x16_f16(af[1], bfv[1], acc[1][1], 0, 0, 0); \
            acc[2][0] = __builtin_amdgcn_mfma_f32_32x32x16_f16(af[2], bfv[0], acc[2][0], 0, 0, 0); \
            acc[2][1] = __builtin_amdgcn_mfma_f32_32x32x16_f16(af[2], bfv[1], acc[2][1], 0, 0, 0); \
            acc[3][0] = __builtin_amdgcn_mfma_f32_32x32x16_f16(af[3], bfv[0], acc[3][0], 0, 0, 0); \
            acc[3][1] = __builtin_amdgcn_mfma_f32_32x32x16_f16(af[3], bfv[1], acc[3][1], 0, 0, 0); \
            __builtin_amdgcn_s_setprio(0);                                    \
        }                                                                     \
    }

#define BODY(KT, VM, DOSTAGE)                                                 \
    {                                                                         \
        if (DOSTAGE) STAGE(((KT) + 1) & 1, (KT) + 1);                         \
        __builtin_amdgcn_sched_barrier(0);                                    \
        asm volatile("s_waitcnt vmcnt(" #VM ")" ::: "memory");                \
        __builtin_amdgcn_s_barrier();                                         \
        __builtin_amdgcn_sched_barrier(0);                                    \
        COMPUTE((KT) & 1);                                                    \
        if ((KT) < 7) __builtin_amdgcn_s_barrier();                           \
    }

    STAGE(0, 0);
    BODY(0, 6, 1)
    BODY(1, 6, 1)
    BODY(2, 6, 1)
    BODY(3, 6, 1)
    BODY(4, 6, 1)
    BODY(5, 6, 1)
    BODY(6, 6, 1)
    BODY(7, 0, 0)

#undef BODY
#undef COMPUTE
#undef STAGE

    // epilogue (verified R6/R8)
#pragma unroll
    for (int ni = 0; ni < 2; ++ni) {
#pragma unroll
        for (int g = 0; g < 2; ++g) {
            float M = -1e30f;
#pragma unroll
            for (int m2 = 0; m2 < 2; ++m2)
#pragma unroll
                for (int r = 0; r < 16; ++r) M = fmaxf(M, acc[g * 2 + m2][ni][r]);
            M = fmaxf(M, __shfl_xor(M, 32, 64));
            const float thr = M - 0.5f * MARGIN;
            unsigned long long msk = 0ull;
#pragma unroll
            for (int m2 = 0; m2 < 2; ++m2)
#pragma unroll
                for (int q = 0; q < 4; ++q) {
                    unsigned nib = 0u;
#pragma unroll
                    for (int j = 0; j < 4; ++j)
                        nib |= (acc[g * 2 + m2][ni][q * 4 + j] >= thr) ? (1u << j) : 0u;
                    msk |= (unsigned long long)nib << (m2 * 32 + q * 8 + kh * 4);
                }
            msk |= __shfl_xor(msk, 32, 64);
            if (kh == 0) {
                int n = n0 + wc * 64 + ni * 32 + r31;
                int grp = (p0 >> 6) + wr * 2 + g;
                gmin[(size_t)n * NG + grp] = -2.0f * M;
                maskA[(size_t)n * NG + grp] = msk;
            }
        }
    }
}

// ---------------------------------------------------------------------------
// Kernel 4: pick + codes + loss (fused, verified R11). One wave per row.
// ---------------------------------------------------------------------------
__global__ __launch_bounds__(256) void k_pick(
    const float* __restrict__ gmin, const unsigned long long* __restrict__ maskA,
    const float* __restrict__ zqn, const float* __restrict__ cb_raw,
    const float* __restrict__ rinv, const float* __restrict__ cz2,
    float* __restrict__ idxf, ushort* __restrict__ chi, float* __restrict__ loss)
{
    __shared__ int lst[4][256];
    __shared__ int cnt[4];
    const int t = threadIdx.x;
    const int w = t >> 6;
    const int lane = t & 63;
    const int row = blockIdx.x * 4 + w;

    float4 zr = *reinterpret_cast<const float4*>(&zqn[(size_t)row * CC + lane * 4]);
    float4 gv = *reinterpret_cast<const float4*>(&gmin[(size_t)row * NG + lane * 4]);

    float pm = fminf(fminf(gv.x, gv.y), fminf(gv.z, gv.w));
#pragma unroll
    for (int off = 1; off < 64; off <<= 1) pm = fminf(pm, __shfl_xor(pm, off, 64));
    const float thresh = pm + MARGIN;

    if (lane == 0) cnt[w] = 0;
    __syncthreads();
    {
        const float g4[4] = {gv.x, gv.y, gv.z, gv.w};
#pragma unroll
        for (int j = 0; j < 4; ++j)
            if (g4[j] <= thresh) {
                int pos = atomicAdd(&cnt[w], 1);
                lst[w][pos] = lane * 4 + j;
            }
    }
    __syncthreads();

    const int nc = cnt[w];
    unsigned long long best = ~0ull;
    for (int ci = 0; ci < nc; ++ci) {
        int g = lst[w][ci];
        unsigned long long msk = maskA[(size_t)row * NG + g];
        while (msk) {
            int bit = __ffsll((long long)msk) - 1;
            msk &= msk - 1;
            int p = g * 64 + bit;
            float rv = rinv[p];
            float4 c4 = *reinterpret_cast<const float4*>(&cb_raw[(size_t)p * CC + lane * 4]);
            float part = (c4.x * rv) * zr.x + (c4.y * rv) * zr.y
                       + (c4.z * rv) * zr.z + (c4.w * rv) * zr.w;
#pragma unroll
            for (int off = 1; off < 64; off <<= 1) part += __shfl_xor(part, off, 64);
            float d4 = fmaf(-2.0f, part, 4.0f + cz2[p]);
            unsigned long long pk = ((unsigned long long)__float_as_uint(d4) << 32) | (unsigned)p;
            best = best < pk ? best : pk;
        }
    }
    const int p = (int)(best & 0xffffffffu);
    if (lane == 0) idxf[row] = (float)p;

    const float rv = rinv[p];
    float4 cv = *reinterpret_cast<const float4*>(&cb_raw[(size_t)p * CC + lane * 4]);
    cv.x *= rv; cv.y *= rv; cv.z *= rv; cv.w *= rv;
    ushort4 hv;
    hv.x = f2bf(cv.x); hv.y = f2bf(cv.y); hv.z = f2bf(cv.z); hv.w = f2bf(cv.w);
    *reinterpret_cast<ushort4*>(&chi[(size_t)row * CC + lane * 4]) = hv;
    float4 lsv;
    float dx = zr.x - cv.x, dy = zr.y - cv.y, dz = zr.z - cv.z, dw = zr.w - cv.w;
    lsv.x = BETA_C * dx * dx; lsv.y = BETA_C * dy * dy;
    lsv.z = BETA_C * dz * dz; lsv.w = BETA_C * dw * dw;
    *reinterpret_cast<float4*>(&loss[(size_t)row * CC + lane * 4]) = lsv;
}

// ---------------------------------------------------------------------------
// Kernel 5: out = codes @ W_out + b_out, plain bf16 MFMA (hi only; verified
// R11). Block 128n x 128d, 4 waves 2x2, wave 64x64.
// ---------------------------------------------------------------------------
__global__ __launch_bounds__(256) void k_gemm_out_mfma(
    const ushort* __restrict__ chi, const ushort* __restrict__ wthi,
    const float* __restrict__ bout, float* __restrict__ out)
{
    __shared__ ushort sAh[128 * 64];
    __shared__ ushort sBh[128 * 64];
    const int t = threadIdx.x;
    const int lane = t & 63;
    const int w = t >> 6;
    const int wr = w >> 1;            // n half
    const int wc = w & 1;             // d half
    const int nb = blockIdx.x * 128;
    const int db = blockIdx.y * 128;
    const int kh = lane >> 5;
    const int r31 = lane & 31;

    f32x16 acc[2][2];
#pragma unroll
    for (int mi = 0; mi < 2; ++mi)
#pragma unroll
        for (int ni = 0; ni < 2; ++ni)
#pragma unroll
            for (int r = 0; r < 16; ++r) acc[mi][ni][r] = 0.f;

    const int srow = lane >> 3;
    const int schunk = (lane & 7) ^ srow;
    const size_t rowA = (size_t)(nb + w * 32 + srow) * CC;
    const size_t rowB = (size_t)(db + w * 32 + srow) * CC;
    const char* sAhsrc = (const char*)chi + rowA * 2 + schunk * 16;
    const char* sBhsrc = (const char*)wthi + rowB * 2 + schunk * 16;
    char* dA = (char*)sAh + (w * 32) * 128;
    char* dB = (char*)sBh + (w * 32) * 128;

    const int sx = (r31 & 7) << 4;

    for (int k0 = 0; k0 < CC; k0 += 64) {
        __syncthreads();
#pragma unroll
        for (int i = 0; i < 4; ++i) {
            gload_lds16(sAhsrc + (size_t)i * 8 * (CC * 2) + k0 * 2, dA + i * 1024);
            gload_lds16(sBhsrc + (size_t)i * 8 * (CC * 2) + k0 * 2, dB + i * 1024);
        }
        __syncthreads();
#pragma unroll
        for (int ks = 0; ks < 4; ++ks) {
            const int ko = ((ks * 32 + kh * 16) ^ sx);
            bf16x8 ah[2], bh[2];
#pragma unroll
            for (int mi = 0; mi < 2; ++mi)
                ah[mi] = *reinterpret_cast<const bf16x8*>(
                    (const char*)sAh + (wr * 64 + mi * 32 + r31) * 128 + ko);
#pragma unroll
            for (int ni = 0; ni < 2; ++ni)
                bh[ni] = *reinterpret_cast<const bf16x8*>(
                    (const char*)sBh + (wc * 64 + ni * 32 + r31) * 128 + ko);
#pragma unroll
            for (int mi = 0; mi < 2; ++mi)
#pragma unroll
                for (int ni = 0; ni < 2; ++ni)
                    acc[mi][ni] = __builtin_amdgcn_mfma_f32_32x32x16_bf16(
                        ah[mi], bh[ni], acc[mi][ni], 0, 0, 0);
        }
    }

#pragma unroll
    for (int ni = 0; ni < 2; ++ni) {
        const int d = db + wc * 64 + ni * 32 + r31;
        const float bv = bout[d];
#pragma unroll
        for (int mi = 0; mi < 2; ++mi) {
            const int nbase = nb + wr * 64 + mi * 32 + 4 * kh;
#pragma unroll
            for (int q = 0; q < 4; ++q)
#pragma unroll
                for (int j = 0; j < 4; ++j) {
                    int n = nbase + j + 8 * q;
                    out[(size_t)n * DD + d] = acc[mi][ni][q * 4 + j] + bv;
                }
        }
    }
}

// ---------------------------------------------------------------------------
extern "C" void kernel_launch(void* const* d_in, const int* in_sizes, int n_in,
                              void* d_out, int out_size, void* d_ws, size_t ws_size,
                              hipStream_t stream)
{
    const float* z        = (const float*)d_in[0];
    const float* W_in     = (const float*)d_in[1];
    const float* b_in     = (const float*)d_in[2];
    const float* W_out    = (const float*)d_in[3];
    const float* b_out    = (const float*)d_in[4];
    const float* codebook = (const float*)d_in[5];

    char* ws = (char*)d_ws;
    ushort* zqh   = (ushort*)(ws);                      //  4,194,304
    ushort* cbh   = (ushort*)(ws + 4194304);            //  8,388,608
    ushort* chi   = (ushort*)(ws + 12582912);           //  4,194,304
    ushort* wthi  = (ushort*)(ws + 16777216);           //    393,216
    float*  cz2   = (float*)(ws + 17170432);            //     65,536
    float*  rinv  = (float*)(ws + 17235968);            //     65,536

    float* out  = (float*)d_out;                        // [8192x768]
    float* loss = out + (size_t)NN * DD;                // [8192x256]
    float* idxf = loss + (size_t)NN * CC;               // [8192]

    // scratch aliased into the (unwritten) `out` region (24 MB <= 25.2 MB):
    float* gmin = (float*)d_out;                                      // 8 MB
    unsigned long long* maskA = (unsigned long long*)((char*)d_out + 8388608); // 16 MB
    float* zq = loss;   // f32 zq lives in the loss region until k_pick

    k_gemm_in_norm<<<NN / 16, 256, 0, stream>>>(z, W_in, b_in, zq, zqh);
    k_prep<<<PP / 4 + 48, 256, 0, stream>>>(codebook, cbh, cz2, rinv, W_out, wthi);
    k_dist<<<dim3(PP / 256, NN / 128), 256, 0, stream>>>(cbh, zqh, cz2, gmin, maskA);
    k_pick<<<NN / 4, 256, 0, stream>>>(gmin, maskA, zq, codebook, rinv, cz2,
                                       idxf, chi, loss);
    k_gemm_out_mfma<<<dim3(NN / 128, DD / 128), 256, 0, stream>>>(chi, wthi, b_out, out);
}

// Round 13
// 177.121 us; speedup vs baseline: 1.2941x; 1.2941x over previous
//
#include <hip/hip_runtime.h>
#include <hip/hip_fp16.h>
#include <math.h>

#define NN 8192
#define DD 768
#define CC 256
#define PP 16384
#define NG 256            // 64-wide codebook groups
#define MARGIN 5.0e-3f    // > 2*eps_dist(fp16)=2e-3
#define BETA_C 1.25f
#define EPS_C 1e-12f

typedef __attribute__((ext_vector_type(8))) _Float16 f16x8;
typedef __attribute__((ext_vector_type(8))) short bf16x8;
typedef __attribute__((ext_vector_type(4))) float f32x4;
typedef __attribute__((ext_vector_type(16))) float f32x16;

static __device__ __forceinline__ ushort f2h(float x) {
    _Float16 h = (_Float16)x;            // RNE
    return __builtin_bit_cast(unsigned short, h);
}
static __device__ __forceinline__ ushort f2bf(float x) {
    unsigned u = __float_as_uint(x);
    return (ushort)((u + 0x7fffu + ((u >> 16) & 1u)) >> 16);
}

static __device__ __forceinline__ void gload_lds16(const void* g, void* l) {
    __builtin_amdgcn_global_load_lds(
        (const __attribute__((address_space(1))) unsigned int*)g,
        (__attribute__((address_space(3))) unsigned int*)l, 16, 0, 0);
}

// ---------------------------------------------------------------------------
// Kernel 1: zq_pre = z @ W_in + b_in  [8192x256], K=768. f32, the R2/R5-
// verified 64x64 tile (summation order is load-bearing for the argmin).
// ---------------------------------------------------------------------------
__global__ __launch_bounds__(256) void k_gemm_in(const float* __restrict__ z,
    const float* __restrict__ W, const float* __restrict__ b,
    float* __restrict__ zq)
{
    __shared__ float zt[64][36];
    __shared__ float wt[32][68];
    const int t = threadIdx.x;
    const int ti = t >> 4, tj = t & 15;
    const int n0 = blockIdx.x * 64;
    const int c0 = blockIdx.y * 64;

    f32x4 acc[4];
#pragma unroll
    for (int r = 0; r < 4; ++r) acc[r] = (f32x4){0.f, 0.f, 0.f, 0.f};

    for (int k0 = 0; k0 < DD; k0 += 32) {
        __syncthreads();
#pragma unroll
        for (int l = 0; l < 2; ++l) {
            int idx = l * 256 + t;
            int row = idx >> 3, c4 = idx & 7;
            *reinterpret_cast<float4*>(&zt[row][c4 * 4]) =
                *reinterpret_cast<const float4*>(&z[(size_t)(n0 + row) * DD + k0 + c4 * 4]);
            int krow = idx >> 4, w4 = idx & 15;
            *reinterpret_cast<float4*>(&wt[krow][w4 * 4]) =
                *reinterpret_cast<const float4*>(&W[(size_t)(k0 + krow) * CC + c0 + w4 * 4]);
        }
        __syncthreads();
#pragma unroll
        for (int kk = 0; kk < 32; kk += 4) {
            float4 a4[4], b4[4];
#pragma unroll
            for (int r = 0; r < 4; ++r)
                a4[r] = *reinterpret_cast<const float4*>(&zt[ti * 4 + r][kk]);
#pragma unroll
            for (int q = 0; q < 4; ++q)
                b4[q] = *reinterpret_cast<const float4*>(&wt[kk + q][tj * 4]);
#pragma unroll
            for (int q = 0; q < 4; ++q)
#pragma unroll
                for (int r = 0; r < 4; ++r) {
                    float av = ((const float*)&a4[r])[q];
                    acc[r].x += av * b4[q].x;
                    acc[r].y += av * b4[q].y;
                    acc[r].z += av * b4[q].z;
                    acc[r].w += av * b4[q].w;
                }
        }
    }
#pragma unroll
    for (int r = 0; r < 4; ++r) {
        int col = c0 + tj * 4;
        float4 o;
        o.x = acc[r].x + b[col];
        o.y = acc[r].y + b[col + 1];
        o.z = acc[r].z + b[col + 2];
        o.w = acc[r].w + b[col + 3];
        *reinterpret_cast<float4*>(&zq[(size_t)(n0 + ti * 4 + r) * CC + col]) = o;
    }
}

// ---------------------------------------------------------------------------
// Kernel 2: row L2-normalize (NN rows): f32 in-place + fp16 out (verified).
// ---------------------------------------------------------------------------
__global__ __launch_bounds__(256) void k_norm2(const float* __restrict__ src,
    float* __restrict__ dstf32, ushort* __restrict__ dsth, int rows)
{
    const int wave = threadIdx.x >> 6;
    const int lane = threadIdx.x & 63;
    const int row = blockIdx.x * 4 + wave;
    if (row >= rows) return;
    float4 v = *reinterpret_cast<const float4*>(&src[(size_t)row * CC + lane * 4]);
    float s = v.x * v.x + v.y * v.y + v.z * v.z + v.w * v.w;
#pragma unroll
    for (int off = 32; off; off >>= 1) s += __shfl_xor(s, off, 64);
    float r = 1.0f / sqrtf(s + EPS_C);
    v.x *= r; v.y *= r; v.z *= r; v.w *= r;
    *reinterpret_cast<float4*>(&dstf32[(size_t)row * CC + lane * 4]) = v;
    ushort4 hv;
    hv.x = f2h(v.x); hv.y = f2h(v.y); hv.z = f2h(v.z); hv.w = f2h(v.w);
    *reinterpret_cast<ushort4*>(&dsth[(size_t)row * CC + lane * 4]) = hv;
}

// ---------------------------------------------------------------------------
// Kernel 3 (merged prep, verified R11): blocks [0,4096): codebook normalize
// -> cbh (fp16), cz2, rinv. Blocks [4096,4144): W_out -> transposed hi bf16.
// ---------------------------------------------------------------------------
__global__ __launch_bounds__(256) void k_prep(const float* __restrict__ codebook,
    ushort* __restrict__ cbh, float* __restrict__ cz2, float* __restrict__ rinv,
    const float* __restrict__ W, ushort* __restrict__ wthi)
{
    __shared__ float tile[64][68];
    const int t = threadIdx.x;
    if (blockIdx.x < 4096) {
        const int wave = t >> 6;
        const int lane = t & 63;
        const int row = blockIdx.x * 4 + wave;
        float4 v = *reinterpret_cast<const float4*>(&codebook[(size_t)row * CC + lane * 4]);
        float s = v.x * v.x + v.y * v.y + v.z * v.z + v.w * v.w;
#pragma unroll
        for (int off = 32; off; off >>= 1) s += __shfl_xor(s, off, 64);
        float r = 1.0f / sqrtf(s + EPS_C);
        v.x *= r; v.y *= r; v.z *= r; v.w *= r;
        ushort4 hv;
        hv.x = f2h(v.x); hv.y = f2h(v.y); hv.z = f2h(v.z); hv.w = f2h(v.w);
        *reinterpret_cast<ushort4*>(&cbh[(size_t)row * CC + lane * 4]) = hv;
        float s2 = v.x * v.x + v.y * v.y + v.z * v.z + v.w * v.w;
#pragma unroll
        for (int off = 32; off; off >>= 1) s2 += __shfl_xor(s2, off, 64);
        if (lane == 0) {
            cz2[row] = s2;
            rinv[row] = r;
        }
    } else {
        const int id = blockIdx.x - 4096;          // 0..47
        const int d0 = (id % 12) * 64;
        const int k0 = (id / 12) * 64;
#pragma unroll
        for (int i = 0; i < 16; ++i) {
            int row = i * 4 + (t >> 6);
            int col = t & 63;
            tile[row][col] = W[(size_t)(k0 + row) * DD + d0 + col];
        }
        __syncthreads();
#pragma unroll
        for (int i = 0; i < 16; ++i) {
            int drow = i * 4 + (t >> 6);
            int kc = t & 63;
            wthi[(size_t)(d0 + drow) * CC + k0 + kc] = f2bf(tile[kc][drow]);
        }
    }
}

// ---------------------------------------------------------------------------
// Kernel 4: fp16 MFMA approx distances — the VERIFIED R8 kernel, verbatim
// (256p x 128n, 4 waves, BK=32, 2 x 24 KB LDS dbuf, counted vmcnt(6),
// XOR-swizzled rows, 2D grid). 97 us / MfmaUtil 31% / FETCH 23 MB.
// ---------------------------------------------------------------------------
__global__ __launch_bounds__(256) void k_dist(
    const ushort* __restrict__ cbh, const ushort* __restrict__ zqh,
    const float* __restrict__ cz2,
    float* __restrict__ gmin, unsigned long long* __restrict__ maskA)
{
    __shared__ ushort lds[2][12288];  // 48 KB total
    const int t = threadIdx.x;
    const int lane = t & 63;
    const int w = t >> 6;             // wave 0..3
    const int wr = w >> 1;            // p half (128 rows)
    const int wc = w & 1;             // n half (64 cols)
    const int p0 = blockIdx.x * 256;
    const int n0 = blockIdx.y * 128;
    const int kh = lane >> 5;
    const int r31 = lane & 31;

    // acc init with -cz2/2
    f32x16 acc[4][2];
#pragma unroll
    for (int mi = 0; mi < 4; ++mi) {
        const int pbm = p0 + wr * 128 + mi * 32;
#pragma unroll
        for (int q = 0; q < 4; ++q) {
            float4 cz = *reinterpret_cast<const float4*>(&cz2[pbm + q * 8 + kh * 4]);
#pragma unroll
            for (int j = 0; j < 4; ++j) {
                float v = -0.5f * ((const float*)&cz.x)[j];
                acc[mi][0][q * 4 + j] = v;
                acc[mi][1][q * 4 + j] = v;
            }
        }
    }

    // staging sources (pre-swizzled global; mapping verified R6/R8)
    const int u_l = lane >> 3;
    const int e = (lane & 7) ^ u_l;
    const int hh = e >> 2, jj = e & 3;
    const ushort* srcA[4];
    const ushort* srcB[2];
#pragma unroll
    for (int i = 0; i < 4; ++i)
        srcA[i] = cbh + (size_t)(p0 + 2 * (w * 32 + i * 8 + u_l) + hh) * CC + jj * 8;
#pragma unroll
    for (int i = 0; i < 2; ++i)
        srcB[i] = zqh + (size_t)(n0 + 2 * (w * 16 + i * 8 + u_l) + hh) * CC + jj * 8;

#define STAGE(BUF, KT)                                                        \
    {                                                                         \
        _Pragma("unroll")                                                     \
        for (int i = 0; i < 4; ++i)                                           \
            gload_lds16(srcA[i] + (KT) * 32, &lds[BUF][(w * 32 + i * 8) * 64]); \
        _Pragma("unroll")                                                     \
        for (int i = 0; i < 2; ++i)                                           \
            gload_lds16(srcB[i] + (KT) * 32, &lds[BUF][8192 + (w * 16 + i * 8) * 64]); \
    }

    // read-side addressing (verified R6/R8)
    const int ua = wr * 64 + (r31 >> 1);   // + mi*16
    const int ub = wc * 32 + (r31 >> 1);   // + ni*16
    const int hb = (r31 & 1) * 4 + kh;     // + ks*2

#define COMPUTE(BUF)                                                          \
    {                                                                         \
        _Pragma("unroll")                                                     \
        for (int ks = 0; ks < 2; ++ks) {                                      \
            f16x8 af[4], bfv[2];                                              \
            _Pragma("unroll")                                                 \
            for (int mi = 0; mi < 4; ++mi) {                                  \
                int u = ua + mi * 16;                                         \
                af[mi] = *reinterpret_cast<const f16x8*>(                     \
                    &lds[BUF][u * 64 + (((hb + ks * 2) ^ (u & 7)) * 8)]);     \
            }                                                                 \
            _Pragma("unroll")                                                 \
            for (int ni = 0; ni < 2; ++ni) {                                  \
                int u = ub + ni * 16;                                         \
                bfv[ni] = *reinterpret_cast<const f16x8*>(                    \
                    &lds[BUF][8192 + u * 64 + (((hb + ks * 2) ^ (u & 7)) * 8)]); \
            }                                                                 \
            __builtin_amdgcn_s_setprio(1);                                    \
            acc[0][0] = __builtin_amdgcn_mfma_f32_32x32x16_f16(af[0], bfv[0], acc[0][0], 0, 0, 0); \
            acc[0][1] = __builtin_amdgcn_mfma_f32_32x32x16_f16(af[0], bfv[1], acc[0][1], 0, 0, 0); \
            acc[1][0] = __builtin_amdgcn_mfma_f32_32x32x16_f16(af[1], bfv[0], acc[1][0], 0, 0, 0); \
            acc[1][1] = __builtin_amdgcn_mfma_f32_32x32x16_f16(af[1], bfv[1], acc[1][1], 0, 0, 0); \
            acc[2][0] = __builtin_amdgcn_mfma_f32_32x32x16_f16(af[2], bfv[0], acc[2][0], 0, 0, 0); \
            acc[2][1] = __builtin_amdgcn_mfma_f32_32x32x16_f16(af[2], bfv[1], acc[2][1], 0, 0, 0); \
            acc[3][0] = __builtin_amdgcn_mfma_f32_32x32x16_f16(af[3], bfv[0], acc[3][0], 0, 0, 0); \
            acc[3][1] = __builtin_amdgcn_mfma_f32_32x32x16_f16(af[3], bfv[1], acc[3][1], 0, 0, 0); \
            __builtin_amdgcn_s_setprio(0);                                    \
        }                                                                     \
    }

#define BODY(KT, VM, DOSTAGE)                                                 \
    {                                                                         \
        if (DOSTAGE) STAGE(((KT) + 1) & 1, (KT) + 1);                         \
        __builtin_amdgcn_sched_barrier(0);                                    \
        asm volatile("s_waitcnt vmcnt(" #VM ")" ::: "memory");                \
        __builtin_amdgcn_s_barrier();                                         \
        __builtin_amdgcn_sched_barrier(0);                                    \
        COMPUTE((KT) & 1);                                                    \
        if ((KT) < 7) __builtin_amdgcn_s_barrier();                           \
    }

    STAGE(0, 0);
    BODY(0, 6, 1)
    BODY(1, 6, 1)
    BODY(2, 6, 1)
    BODY(3, 6, 1)
    BODY(4, 6, 1)
    BODY(5, 6, 1)
    BODY(6, 6, 1)
    BODY(7, 0, 0)

#undef BODY
#undef COMPUTE
#undef STAGE

    // epilogue (verified R6/R8)
#pragma unroll
    for (int ni = 0; ni < 2; ++ni) {
#pragma unroll
        for (int g = 0; g < 2; ++g) {
            float M = -1e30f;
#pragma unroll
            for (int m2 = 0; m2 < 2; ++m2)
#pragma unroll
                for (int r = 0; r < 16; ++r) M = fmaxf(M, acc[g * 2 + m2][ni][r]);
            M = fmaxf(M, __shfl_xor(M, 32, 64));
            const float thr = M - 0.5f * MARGIN;
            unsigned long long msk = 0ull;
#pragma unroll
            for (int m2 = 0; m2 < 2; ++m2)
#pragma unroll
                for (int q = 0; q < 4; ++q) {
                    unsigned nib = 0u;
#pragma unroll
                    for (int j = 0; j < 4; ++j)
                        nib |= (acc[g * 2 + m2][ni][q * 4 + j] >= thr) ? (1u << j) : 0u;
                    msk |= (unsigned long long)nib << (m2 * 32 + q * 8 + kh * 4);
                }
            msk |= __shfl_xor(msk, 32, 64);
            if (kh == 0) {
                int n = n0 + wc * 64 + ni * 32 + r31;
                int grp = (p0 >> 6) + wr * 2 + g;
                gmin[(size_t)n * NG + grp] = -2.0f * M;
                maskA[(size_t)n * NG + grp] = msk;
            }
        }
    }
}

// ---------------------------------------------------------------------------
// Kernel 5: pick + codes + loss (fused, verified R11). One wave per row.
// ---------------------------------------------------------------------------
__global__ __launch_bounds__(256) void k_pick(
    const float* __restrict__ gmin, const unsigned long long* __restrict__ maskA,
    const float* __restrict__ zqn, const float* __restrict__ cb_raw,
    const float* __restrict__ rinv, const float* __restrict__ cz2,
    float* __restrict__ idxf, ushort* __restrict__ chi, float* __restrict__ loss)
{
    __shared__ int lst[4][256];
    __shared__ int cnt[4];
    const int t = threadIdx.x;
    const int w = t >> 6;
    const int lane = t & 63;
    const int row = blockIdx.x * 4 + w;

    float4 zr = *reinterpret_cast<const float4*>(&zqn[(size_t)row * CC + lane * 4]);
    float4 gv = *reinterpret_cast<const float4*>(&gmin[(size_t)row * NG + lane * 4]);

    float pm = fminf(fminf(gv.x, gv.y), fminf(gv.z, gv.w));
#pragma unroll
    for (int off = 1; off < 64; off <<= 1) pm = fminf(pm, __shfl_xor(pm, off, 64));
    const float thresh = pm + MARGIN;

    if (lane == 0) cnt[w] = 0;
    __syncthreads();
    {
        const float g4[4] = {gv.x, gv.y, gv.z, gv.w};
#pragma unroll
        for (int j = 0; j < 4; ++j)
            if (g4[j] <= thresh) {
                int pos = atomicAdd(&cnt[w], 1);
                lst[w][pos] = lane * 4 + j;
            }
    }
    __syncthreads();

    const int nc = cnt[w];
    unsigned long long best = ~0ull;
    for (int ci = 0; ci < nc; ++ci) {
        int g = lst[w][ci];
        unsigned long long msk = maskA[(size_t)row * NG + g];
        while (msk) {
            int bit = __ffsll((long long)msk) - 1;
            msk &= msk - 1;
            int p = g * 64 + bit;
            float rv = rinv[p];
            float4 c4 = *reinterpret_cast<const float4*>(&cb_raw[(size_t)p * CC + lane * 4]);
            float part = (c4.x * rv) * zr.x + (c4.y * rv) * zr.y
                       + (c4.z * rv) * zr.z + (c4.w * rv) * zr.w;
#pragma unroll
            for (int off = 1; off < 64; off <<= 1) part += __shfl_xor(part, off, 64);
            float d4 = fmaf(-2.0f, part, 4.0f + cz2[p]);
            unsigned long long pk = ((unsigned long long)__float_as_uint(d4) << 32) | (unsigned)p;
            best = best < pk ? best : pk;
        }
    }
    const int p = (int)(best & 0xffffffffu);
    if (lane == 0) idxf[row] = (float)p;

    const float rv = rinv[p];
    float4 cv = *reinterpret_cast<const float4*>(&cb_raw[(size_t)p * CC + lane * 4]);
    cv.x *= rv; cv.y *= rv; cv.z *= rv; cv.w *= rv;
    ushort4 hv;
    hv.x = f2bf(cv.x); hv.y = f2bf(cv.y); hv.z = f2bf(cv.z); hv.w = f2bf(cv.w);
    *reinterpret_cast<ushort4*>(&chi[(size_t)row * CC + lane * 4]) = hv;
    float4 lsv;
    float dx = zr.x - cv.x, dy = zr.y - cv.y, dz = zr.z - cv.z, dw = zr.w - cv.w;
    lsv.x = BETA_C * dx * dx; lsv.y = BETA_C * dy * dy;
    lsv.z = BETA_C * dz * dz; lsv.w = BETA_C * dw * dw;
    *reinterpret_cast<float4*>(&loss[(size_t)row * CC + lane * 4]) = lsv;
}

// ---------------------------------------------------------------------------
// Kernel 6: out = codes @ W_out + b_out, plain bf16 MFMA (hi only; verified
// R11). Block 128n x 128d, 4 waves 2x2, wave 64x64.
// ---------------------------------------------------------------------------
__global__ __launch_bounds__(256) void k_gemm_out_mfma(
    const ushort* __restrict__ chi, const ushort* __restrict__ wthi,
    const float* __restrict__ bout, float* __restrict__ out)
{
    __shared__ ushort sAh[128 * 64];
    __shared__ ushort sBh[128 * 64];
    const int t = threadIdx.x;
    const int lane = t & 63;
    const int w = t >> 6;
    const int wr = w >> 1;            // n half
    const int wc = w & 1;             // d half
    const int nb = blockIdx.x * 128;
    const int db = blockIdx.y * 128;
    const int kh = lane >> 5;
    const int r31 = lane & 31;

    f32x16 acc[2][2];
#pragma unroll
    for (int mi = 0; mi < 2; ++mi)
#pragma unroll
        for (int ni = 0; ni < 2; ++ni)
#pragma unroll
            for (int r = 0; r < 16; ++r) acc[mi][ni][r] = 0.f;

    const int srow = lane >> 3;
    const int schunk = (lane & 7) ^ srow;
    const size_t rowA = (size_t)(nb + w * 32 + srow) * CC;
    const size_t rowB = (size_t)(db + w * 32 + srow) * CC;
    const char* sAhsrc = (const char*)chi + rowA * 2 + schunk * 16;
    const char* sBhsrc = (const char*)wthi + rowB * 2 + schunk * 16;
    char* dA = (char*)sAh + (w * 32) * 128;
    char* dB = (char*)sBh + (w * 32) * 128;

    const int sx = (r31 & 7) << 4;

    for (int k0 = 0; k0 < CC; k0 += 64) {
        __syncthreads();
#pragma unroll
        for (int i = 0; i < 4; ++i) {
            gload_lds16(sAhsrc + (size_t)i * 8 * (CC * 2) + k0 * 2, dA + i * 1024);
            gload_lds16(sBhsrc + (size_t)i * 8 * (CC * 2) + k0 * 2, dB + i * 1024);
        }
        __syncthreads();
#pragma unroll
        for (int ks = 0; ks < 4; ++ks) {
            const int ko = ((ks * 32 + kh * 16) ^ sx);
            bf16x8 ah[2], bh[2];
#pragma unroll
            for (int mi = 0; mi < 2; ++mi)
                ah[mi] = *reinterpret_cast<const bf16x8*>(
                    (const char*)sAh + (wr * 64 + mi * 32 + r31) * 128 + ko);
#pragma unroll
            for (int ni = 0; ni < 2; ++ni)
                bh[ni] = *reinterpret_cast<const bf16x8*>(
                    (const char*)sBh + (wc * 64 + ni * 32 + r31) * 128 + ko);
#pragma unroll
            for (int mi = 0; mi < 2; ++mi)
#pragma unroll
                for (int ni = 0; ni < 2; ++ni)
                    acc[mi][ni] = __builtin_amdgcn_mfma_f32_32x32x16_bf16(
                        ah[mi], bh[ni], acc[mi][ni], 0, 0, 0);
        }
    }

#pragma unroll
    for (int ni = 0; ni < 2; ++ni) {
        const int d = db + wc * 64 + ni * 32 + r31;
        const float bv = bout[d];
#pragma unroll
        for (int mi = 0; mi < 2; ++mi) {
            const int nbase = nb + wr * 64 + mi * 32 + 4 * kh;
#pragma unroll
            for (int q = 0; q < 4; ++q)
#pragma unroll
                for (int j = 0; j < 4; ++j) {
                    int n = nbase + j + 8 * q;
                    out[(size_t)n * DD + d] = acc[mi][ni][q * 4 + j] + bv;
                }
        }
    }
}

// ---------------------------------------------------------------------------
extern "C" void kernel_launch(void* const* d_in, const int* in_sizes, int n_in,
                              void* d_out, int out_size, void* d_ws, size_t ws_size,
                              hipStream_t stream)
{
    const float* z        = (const float*)d_in[0];
    const float* W_in     = (const float*)d_in[1];
    const float* b_in     = (const float*)d_in[2];
    const float* W_out    = (const float*)d_in[3];
    const float* b_out    = (const float*)d_in[4];
    const float* codebook = (const float*)d_in[5];

    char* ws = (char*)d_ws;
    ushort* zqh   = (ushort*)(ws);                      //  4,194,304
    ushort* cbh   = (ushort*)(ws + 4194304);            //  8,388,608
    ushort* chi   = (ushort*)(ws + 12582912);           //  4,194,304
    ushort* wthi  = (ushort*)(ws + 16777216);           //    393,216
    float*  cz2   = (float*)(ws + 17170432);            //     65,536
    float*  rinv  = (float*)(ws + 17235968);            //     65,536

    float* out  = (float*)d_out;                        // [8192x768]
    float* loss = out + (size_t)NN * DD;                // [8192x256]
    float* idxf = loss + (size_t)NN * CC;               // [8192]

    // scratch aliased into the (unwritten) `out` region (24 MB <= 25.2 MB):
    float* gmin = (float*)d_out;                                      // 8 MB
    unsigned long long* maskA = (unsigned long long*)((char*)d_out + 8388608); // 16 MB
    float* zq = loss;   // f32 zq lives in the loss region until k_pick

    k_gemm_in<<<dim3(NN / 64, CC / 64), 256, 0, stream>>>(z, W_in, b_in, zq);
    k_norm2<<<NN / 4, 256, 0, stream>>>(zq, zq, zqh, NN);
    k_prep<<<PP / 4 + 48, 256, 0, stream>>>(codebook, cbh, cz2, rinv, W_out, wthi);
    k_dist<<<dim3(PP / 256, NN / 128), 256, 0, stream>>>(cbh, zqh, cz2, gmin, maskA);
    k_pick<<<NN / 4, 256, 0, stream>>>(gmin, maskA, zq, codebook, rinv, cz2,
                                       idxf, chi, loss);
    k_gemm_out_mfma<<<dim3(NN / 128, DD / 128), 256, 0, stream>>>(chi, wthi, b_out, out);
}